// Round 7
// baseline (190.980 us; speedup 1.0000x reference)
//
#include <hip/hip_runtime.h>

typedef _Float16 f16;
typedef _Float16 f16x8 __attribute__((ext_vector_type(8)));
typedef _Float16 f16x4 __attribute__((ext_vector_type(4)));
typedef float f32x4 __attribute__((ext_vector_type(4)));

#define B_TOT 128

// ---------------- helpers ----------------
__device__ __forceinline__ void gload_lds16(const void* g, void* l) {
  __builtin_amdgcn_global_load_lds(
      (const __attribute__((address_space(1))) void*)g,
      (__attribute__((address_space(3))) void*)l, 16, 0, 0);
}

__device__ __forceinline__ float rcpf(float x) { return __builtin_amdgcn_rcpf(x); }

// ---------------- kernel 1: weight convert + transpose ----------------
// W[k][n] f32 (256x512) -> Wt[n][k] f16 (512x256), 3 weights
__global__ void __launch_bounds__(256) cvt_w(const float* __restrict__ Wr,
                                             const float* __restrict__ Wz,
                                             const float* __restrict__ Wh,
                                             f16* __restrict__ Wt) {
  int idx = blockIdx.x * 256 + threadIdx.x;      // < 3*131072
  int w = idx >> 17;
  int rem = idx & 131071;
  int n = rem >> 8;
  int k = rem & 255;
  const float* W = (w == 0) ? Wr : ((w == 1) ? Wz : Wh);
  Wt[(size_t)w * 131072 + n * 256 + k] = (f16)W[k * 512 + n];
}

// ---------------- kernel 2: fused GEMM + scan, P lives in LDS ----------------
// Grid = 512 blocks: b = bid&127, ns = bid>>7 (h-slice of 128).
// Per block: for mt in 0..3 (t-tiles of 128):
//   GEMM 128t x (128h x 3w), K=256: nt in 0..1, kt in 0..7 (BK=32),
//   counted-vmcnt depth-2 double-buffer (7 gload_lds per wave per tile:
//   A 4 chunks f32 direct from x, B 3 chunks f16 from Wt).
//   Epilogue -> P in LDS [w][tg16][h128][8t] f16 (96 KB).
//   Then 128 threads scan the 128 t-steps (h-state in regs across mt).
// LDS: 2 x 28 KB staging + 96 KB P = 152 KB -> 1 block/CU.
__global__ void __launch_bounds__(256, 1) brc_fused(
    const float* __restrict__ X32,
    const f16* __restrict__ Wr, const f16* __restrict__ Wz, const f16* __restrict__ Wh,
    const float* __restrict__ h0, const float* __restrict__ mr,
    const float* __restrict__ mz, const float* __restrict__ br,
    const float* __restrict__ bz, float* __restrict__ out) {
  __shared__ __align__(16) char lds[155648];
  const int tid = threadIdx.x;
  const int wid = tid >> 6, lane = tid & 63;
  const int b = blockIdx.x & 127, ns = blockIdx.x >> 7;
  const int wr = wid >> 1, wc = wid & 1;         // 2x2 waves, wave tile 64x32

  const char* Xb  = (const char*)(X32 + (size_t)b * 131072);      // f32 rows
  const char* WrC = (const char*)Wr + (size_t)ns * 128 * 512;     // h-slice base
  const char* WzC = (const char*)Wz + (size_t)ns * 128 * 512;
  const char* WhC = (const char*)Wh + (size_t)ns * 128 * 512;
  f16* Pl = (f16*)(lds + 57344);

  f32x4 acc[3][4][2] = {};

  // scan state (threads 0..127 own chain h = ns*128 + tid)
  float h = 0.f, mrc = 0.f, mzc = 0.f, br2 = 0.f, nbz = 0.f;
  if (tid < 128) {
    int hg = ns * 128 + tid;
    h = h0[(size_t)b * 512 + hg];
    mrc = 2.0f * mr[hg]; mzc = -mz[hg];
    br2 = 2.0f * br[hg]; nbz = -bz[hg];
  }

  // stage tile t2 (linear index, 0..63): buf = t2&1.
  // A: [p4][h2 2][row128][16B] f32 (16 KB); B: [w3][p4][col64][16B] f16 (12 KB)
#define STAGE(t2)                                                             \
  do {                                                                        \
    const int mt2_ = (t2) >> 4, nt2_ = ((t2) >> 3) & 1, kt2_ = (t2) & 7;      \
    char* lb_ = lds + ((t2) & 1) * 28672;                                     \
    const int h2_ = wid >> 1, row_ = (wid & 1) * 64 + lane;                   \
    _Pragma("unroll") for (int c = 0; c < 4; ++c) {                           \
      gload_lds16(Xb + ((size_t)(mt2_ * 128 + row_)) * 1024 +                 \
                      kt2_ * 128 + c * 32 + h2_ * 16,                         \
                  lb_ + c * 4096 + wid * 1024);                               \
    }                                                                         \
    _Pragma("unroll") for (int j = 0; j < 3; ++j) {                           \
      int e_ = wid * 3 + j, w3_ = e_ >> 2, p_ = e_ & 3;                       \
      const char* W_ = (w3_ == 0) ? WrC : ((w3_ == 1) ? WzC : WhC);           \
      gload_lds16(W_ + (size_t)(nt2_ * 64 + lane) * 512 + kt2_ * 64 + p_ * 16,\
                  lb_ + 16384 + w3_ * 4096 + p_ * 1024);                      \
    }                                                                         \
  } while (0)

#define WAITV(n) asm volatile("s_waitcnt vmcnt(" #n ")" ::: "memory")

  STAGE(0);
  STAGE(1);

  const int kq = lane >> 4, rl = lane & 15;
  const int col = lane & 15, rbase = (lane >> 4) * 4;

  for (int mt = 0; mt < 4; ++mt) {
    for (int nt = 0; nt < 2; ++nt) {
#pragma unroll
      for (int kt = 0; kt < 8; ++kt) {
        const int tt = (mt * 2 + nt) * 8 + kt;
        if (tt < 63) { WAITV(7); } else { WAITV(0); }   // tile tt landed
        __builtin_amdgcn_s_barrier();
        __builtin_amdgcn_sched_barrier(0);
        const char* lb = lds + (tt & 1) * 28672;
        __builtin_amdgcn_s_setprio(1);
        f16x8 a[4], bf[3][2];
#pragma unroll
        for (int mi = 0; mi < 4; ++mi) {
          const float* ap = (const float*)(lb + kq * 4096 +
                                           (wr * 64 + mi * 16 + rl) * 16);
          f32x4 lo = *(const f32x4*)ap;
          f32x4 hi = *(const f32x4*)(ap + 512);     // +2048 B = h2 plane
#pragma unroll
          for (int e = 0; e < 4; ++e) {
            a[mi][e] = (f16)lo[e];
            a[mi][4 + e] = (f16)hi[e];
          }
        }
#pragma unroll
        for (int w = 0; w < 3; ++w)
#pragma unroll
          for (int ni = 0; ni < 2; ++ni)
            bf[w][ni] = *(const f16x8*)(lb + 16384 + w * 4096 + kq * 1024 +
                                        (wc * 32 + ni * 16 + rl) * 16);
#pragma unroll
        for (int w = 0; w < 3; ++w)
#pragma unroll
          for (int mi = 0; mi < 4; ++mi)
#pragma unroll
            for (int ni = 0; ni < 2; ++ni)
              acc[w][mi][ni] = __builtin_amdgcn_mfma_f32_16x16x32_f16(
                  a[mi], bf[w][ni], acc[w][mi][ni], 0, 0, 0);
        __builtin_amdgcn_s_setprio(0);
        __builtin_amdgcn_sched_barrier(0);
        __builtin_amdgcn_s_barrier();               // all waves done reading buf
        if (tt < 62) STAGE(tt + 2);
      }
      // ---- epilogue (mt, nt): acc -> P LDS, then zero acc ----
#pragma unroll
      for (int w = 0; w < 3; ++w)
#pragma unroll
        for (int mi = 0; mi < 4; ++mi) {
          int tl = wr * 64 + mi * 16 + rbase;
#pragma unroll
          for (int ni = 0; ni < 2; ++ni) {
            int hl = nt * 64 + wc * 32 + ni * 16 + col;
            f16x4 v;
#pragma unroll
            for (int r = 0; r < 4; ++r) v[r] = (f16)acc[w][mi][ni][r];
            *(f16x4*)&Pl[w * 16384 + (tl >> 3) * 1024 + hl * 8 + (tl & 7)] = v;
#pragma unroll
            for (int r = 0; r < 4; ++r) acc[w][mi][ni][r] = 0.0f;
          }
        }
    }
    // ---- scan this mt's 128 t-steps ----
    asm volatile("s_waitcnt lgkmcnt(0)" ::: "memory");  // P writes done (own)
    __builtin_amdgcn_s_barrier();                       // all waves' P visible
    __builtin_amdgcn_sched_barrier(0);
    if (tid < 128) {
      const int i = tid;
      const f16* Pr_ = Pl + i * 8;
      const f16* Pz_ = Pl + 16384 + i * 8;
      const f16* Ph_ = Pl + 32768 + i * 8;
      float* opm = out + (((size_t)b * 512 + mt * 128) * 512) + ns * 128 + i;
      f16x8 Ra, Za, Ha, Rb, Zb, Hb;
#define LOADL(R, Z, Hh, g)                                              \
      do {                                                              \
        R  = *(const f16x8*)(Pr_ + (g) * 1024);                         \
        Z  = *(const f16x8*)(Pz_ + (g) * 1024);                         \
        Hh = *(const f16x8*)(Ph_ + (g) * 1024);                         \
      } while (0)
#define STEP8(R, Z, Hh, g)                                              \
      do {                                                              \
        _Pragma("unroll") for (int j = 0; j < 8; ++j) {                 \
          float prs = fmaf((float)R[j], 2.0f, br2);                     \
          float pzs = fmaf((float)Z[j], -1.0f, nbz);                    \
          float ph2 = (float)Hh[j] * 2.0f;                              \
          float er = __expf(fmaf(h, mrc, prs));                         \
          float rr = fmaf(-2.0f, rcpf(er + 1.0f), 2.0f);                \
          float ez = __expf(fmaf(h, mzc, pzs));                         \
          float zz = rcpf(1.0f + ez);                                   \
          float h2v = h + h;                                            \
          float ec = __expf(fmaf(rr, h2v, ph2));                        \
          float cd = fmaf(-2.0f, rcpf(ec + 1.0f), 1.0f);                \
          h = fmaf(zz, h - cd, cd);                                     \
          __builtin_nontemporal_store(h, opm + (size_t)((g) * 8 + j) * 512); \
        }                                                               \
      } while (0)
      LOADL(Ra, Za, Ha, 0);
#pragma unroll
      for (int g = 0; g < 16; g += 2) {
        LOADL(Rb, Zb, Hb, g + 1);
        STEP8(Ra, Za, Ha, g);
        if (g + 2 < 16) LOADL(Ra, Za, Ha, g + 2);
        STEP8(Rb, Zb, Hb, g + 1);
      }
#undef LOADL
#undef STEP8
      WAITV(0);   // drain out-stores so tile-loop vmcnt counting stays exact
    }
    __builtin_amdgcn_s_barrier();   // scan done before next mt's epilogue
  }
#undef STAGE
#undef WAITV
}

// ---------------- launch ----------------
extern "C" void kernel_launch(void* const* d_in, const int* in_sizes, int n_in,
                              void* d_out, int out_size, void* d_ws, size_t ws_size,
                              hipStream_t stream) {
  const float* x  = (const float*)d_in[0];
  const float* h0 = (const float*)d_in[1];
  const float* kr = (const float*)d_in[2];
  const float* kz = (const float*)d_in[3];
  const float* kh = (const float*)d_in[4];
  const float* mr = (const float*)d_in[5];
  const float* mz = (const float*)d_in[6];
  const float* br = (const float*)d_in[7];
  const float* bz = (const float*)d_in[8];
  float* out = (float*)d_out;

  f16* ws = (f16*)d_ws;   // Wt: 3 x 131072 halfs = 768 KB

  cvt_w<<<1536, 256, 0, stream>>>(kr, kz, kh, ws);
  brc_fused<<<512, 256, 0, stream>>>(x, ws, ws + 131072, ws + 262144,
                                     h0, mr, mz, br, bz, out);
}

// Round 8
// 169.494 us; speedup vs baseline: 1.1268x; 1.1268x over previous
//
#include <hip/hip_runtime.h>

typedef _Float16 f16;
typedef _Float16 f16x8 __attribute__((ext_vector_type(8)));
typedef _Float16 f16x4 __attribute__((ext_vector_type(4)));
typedef float f32x4 __attribute__((ext_vector_type(4)));

#define B_TOT 128

// ---------------- helpers ----------------
__device__ __forceinline__ void gload_lds16(const void* g, void* l) {
  __builtin_amdgcn_global_load_lds(
      (const __attribute__((address_space(1))) void*)g,
      (__attribute__((address_space(3))) void*)l, 16, 0, 0);
}

__device__ __forceinline__ float rcpf(float x) { return __builtin_amdgcn_rcpf(x); }

// ---------------- kernel 1: weight convert + transpose ----------------
__global__ void __launch_bounds__(256) cvt_w(const float* __restrict__ Wr,
                                             const float* __restrict__ Wz,
                                             const float* __restrict__ Wh,
                                             f16* __restrict__ Wt) {
  int idx = blockIdx.x * 256 + threadIdx.x;      // < 3*131072
  int w = idx >> 17;
  int rem = idx & 131071;
  int n = rem >> 8;
  int k = rem & 255;
  const float* W = (w == 0) ? Wr : ((w == 1) ? Wz : Wh);
  Wt[(size_t)w * 131072 + n * 256 + k] = (f16)W[k * 512 + n];
}

// ---------------- kernel 2: x convert f32 -> f16 ----------------
__global__ void __launch_bounds__(256) cvt_x(const float4* __restrict__ in,
                                             f16x4* __restrict__ out) {
  int idx = blockIdx.x * 256 + threadIdx.x;
  float4 v = in[idx];
  f16x4 o;
  o[0] = (f16)v.x; o[1] = (f16)v.y; o[2] = (f16)v.z; o[3] = (f16)v.w;
  out[idx] = o;
}

// ---------------- kernel 3: fused 3-weight GEMM, 4-deep counted-vmcnt ----
// X [M][256] f16, Wt [512][256] f16 (pre-transposed).
// P output layout CHUNKED: P[bb][tg(64)][h(512)][8t] f16.
// BM=128, BN=64 (x3 weights), BK=32, 8 K-iterations.
// LDS: FOUR 20 KB buffers (80 KB -> 2 blocks/CU), prefetch depth 3 so the
// issue->wait window is ~3 iterations (~1000+ cy) >= HBM latency (~900 cy).
// Each wave issues exactly 5 gload_lds per tile: steady-state WAITV(15)
// == "3 newer tiles in flight, tile kt landed". Never vmcnt(0) till tail.
__global__ void __launch_bounds__(256) brc_gemm3(
    const f16* __restrict__ X,
    const f16* __restrict__ Wr, const f16* __restrict__ Wz, const f16* __restrict__ Wh,
    f16* __restrict__ Pr, f16* __restrict__ Pz, f16* __restrict__ Ph,
    int Mtiles) {
  __shared__ char lds[81920];          // 4 x 20 KB buffers
  const int tid = threadIdx.x;
  const int wid = tid >> 6, lane = tid & 63;
  const int bid = blockIdx.x;
  const int lid = (bid & 7) * Mtiles + (bid >> 3);   // grid = Mtiles*8, bijective
  const int mt = lid >> 3, nt = lid & 7;             // m-major: 8 lids share mt
  const int m0 = mt * 128, n0 = nt * 64;
  const int wr = wid >> 1, wc = wid & 1;             // 2x2 waves, tile 64x32

  const char* Xc  = (const char*)X + (size_t)m0 * 512;
  const char* WrC = (const char*)Wr + (size_t)n0 * 512;
  const char* WzC = (const char*)Wz + (size_t)n0 * 512;
  const char* WhC = (const char*)Wh + (size_t)n0 * 512;

  f32x4 acc[3][4][2] = {};

  // stage K-tile kt (0..7) into buffer kt&3: 5 gload_lds per thread,
  // exactly 5 per WAVE (vmcnt bookkeeping relies on this).
#define STAGE(kt)                                                             \
  do {                                                                        \
    char* lb_ = lds + ((kt) & 3) * 20480;                                     \
    _Pragma("unroll") for (int c = 0; c < 2; ++c) {  /* A: 8 chunks */        \
      int id_ = c * 4 + wid, p_ = id_ >> 1, rh_ = id_ & 1;                    \
      gload_lds16(Xc + ((size_t)(rh_ * 64 + lane)) * 512 + (kt) * 64 + p_ * 16, \
                  lb_ + p_ * 2048 + rh_ * 1024);                              \
    }                                                                         \
    _Pragma("unroll") for (int j = 0; j < 3; ++j) {  /* B: 12 chunks */       \
      int e_ = wid * 3 + j, w3_ = e_ >> 2, p_ = e_ & 3;                       \
      const char* W_ = (w3_ == 0) ? WrC : ((w3_ == 1) ? WzC : WhC);           \
      gload_lds16(W_ + (size_t)lane * 512 + (kt) * 64 + p_ * 16,              \
                  lb_ + 8192 + w3_ * 4096 + p_ * 1024);                       \
    }                                                                         \
  } while (0)

#define WAITV(n) asm volatile("s_waitcnt vmcnt(" #n ")" ::: "memory")

  STAGE(0);
  STAGE(1);
  STAGE(2);
  STAGE(3);

  const int kq = lane >> 4, rl = lane & 15;
#pragma unroll
  for (int kt = 0; kt < 8; ++kt) {
    // tile kt landed; keep newer tiles in flight (5 loads/wave/tile)
    if (kt <= 4)      { WAITV(15); }
    else if (kt == 5) { WAITV(10); }
    else if (kt == 6) { WAITV(5);  }
    else              { WAITV(0);  }
    __builtin_amdgcn_s_barrier();                  // raw: no vmcnt(0) drain
    __builtin_amdgcn_sched_barrier(0);             // no ds_read hoisting above
    const char* lb = lds + (kt & 3) * 20480;
    __builtin_amdgcn_s_setprio(1);
    f16x8 a[4], b[3][2];
#pragma unroll
    for (int mi = 0; mi < 4; ++mi)
      a[mi] = *(const f16x8*)(lb + kq * 2048 + (wr * 64 + mi * 16 + rl) * 16);
#pragma unroll
    for (int w = 0; w < 3; ++w)
#pragma unroll
      for (int ni = 0; ni < 2; ++ni)
        b[w][ni] = *(const f16x8*)(lb + 8192 + w * 4096 + kq * 1024 +
                                   (wc * 32 + ni * 16 + rl) * 16);
#pragma unroll
    for (int w = 0; w < 3; ++w)
#pragma unroll
      for (int mi = 0; mi < 4; ++mi)
#pragma unroll
        for (int ni = 0; ni < 2; ++ni)
          acc[w][mi][ni] = __builtin_amdgcn_mfma_f32_16x16x32_f16(
              a[mi], b[w][ni], acc[w][mi][ni], 0, 0, 0);
    __builtin_amdgcn_s_setprio(0);
    __builtin_amdgcn_sched_barrier(0);
    __builtin_amdgcn_s_barrier();                  // all waves done reading buf
    if (kt + 4 < 8) STAGE(kt + 4);                 // refill the freed buffer
  }
#undef STAGE
#undef WAITV

  // ---- epilogue: C/D layout col = lane&15, row = (lane>>4)*4 + r ----
  const int col = lane & 15;
  const int rbase = (lane >> 4) * 4;
#pragma unroll
  for (int w = 0; w < 3; ++w) {
    f16* P = (w == 0) ? Pr : ((w == 1) ? Pz : Ph);
#pragma unroll
    for (int mi = 0; mi < 4; ++mi) {
      int m = m0 + wr * 64 + mi * 16 + rbase;
      int bbl = m >> 9;
      int t = m & 511;
      size_t base = ((size_t)bbl * 64 + (t >> 3)) * 4096 + (t & 7);
#pragma unroll
      for (int ni = 0; ni < 2; ++ni) {
        int hcol = n0 + wc * 32 + ni * 16 + col;
        f16x4 v;
#pragma unroll
        for (int r = 0; r < 4; ++r) v[r] = (f16)acc[w][mi][ni][r];
        *(f16x4*)&P[base + (size_t)hcol * 8] = v;
      }
    }
  }
}

// ---------------- kernel 4: recurrent scan ----------------
__global__ void __launch_bounds__(256) brc_scan(
    const f16* __restrict__ Pr, const f16* __restrict__ Pz, const f16* __restrict__ Ph,
    const float* __restrict__ h0, const float* __restrict__ mr, const float* __restrict__ mz,
    const float* __restrict__ br, const float* __restrict__ bz,
    float* __restrict__ out, int b0) {
  int gid = blockIdx.x * 256 + threadIdx.x;   // 0 .. bc*512-1
  int bb = gid >> 9;
  int i = gid & 511;
  float h = h0[((size_t)(b0 + bb) << 9) + i];
  float mrc = 2.0f * mr[i], mzc = -mz[i];
  float br2 = 2.0f * br[i], nbz = -bz[i];
  size_t pbase = ((size_t)bb << 18) + (size_t)i * 8;
  const f16* prp = Pr + pbase;
  const f16* pzp = Pz + pbase;
  const f16* php = Ph + pbase;
  float* op = out + (((size_t)(b0 + bb)) << 18) + i;

  f16x8 Ar, Az, Ah, Br_, Bz_, Bh_, Cr, Cz, Ch, Dr, Dz, Dh;

#define LOADG(R, Z, Hh, g)                                              \
  do {                                                                  \
    R  = __builtin_nontemporal_load((const f16x8*)(prp + ((size_t)(g) << 12))); \
    Z  = __builtin_nontemporal_load((const f16x8*)(pzp + ((size_t)(g) << 12))); \
    Hh = __builtin_nontemporal_load((const f16x8*)(php + ((size_t)(g) << 12))); \
  } while (0)

#define STEP8(R, Z, Hh, g)                                              \
  do {                                                                  \
    _Pragma("unroll") for (int j = 0; j < 8; ++j) {                     \
      float prs = fmaf((float)R[j], 2.0f, br2);                         \
      float pzs = fmaf((float)Z[j], -1.0f, nbz);                        \
      float ph2 = (float)Hh[j] * 2.0f;                                  \
      float er = __expf(fmaf(h, mrc, prs));                             \
      float r  = fmaf(-2.0f, rcpf(er + 1.0f), 2.0f);                    \
      float ez = __expf(fmaf(h, mzc, pzs));                             \
      float z  = rcpf(1.0f + ez);                                       \
      float h2 = h + h;                                                 \
      float ec = __expf(fmaf(r, h2, ph2));                              \
      float cd = fmaf(-2.0f, rcpf(ec + 1.0f), 1.0f);                    \
      h = fmaf(z, h - cd, cd);                                          \
      __builtin_nontemporal_store(h, op + ((size_t)((g) * 8 + j) << 9)); \
    }                                                                   \
  } while (0)

  LOADG(Ar, Az, Ah, 0);
  LOADG(Br_, Bz_, Bh_, 1);
  LOADG(Cr, Cz, Ch, 2);
  for (int g = 0; g < 64; g += 4) {
    LOADG(Dr, Dz, Dh, g + 3);
    STEP8(Ar, Az, Ah, g);
    if (g + 4 < 64) LOADG(Ar, Az, Ah, g + 4);
    STEP8(Br_, Bz_, Bh_, g + 1);
    if (g + 5 < 64) LOADG(Br_, Bz_, Bh_, g + 5);
    STEP8(Cr, Cz, Ch, g + 2);
    if (g + 6 < 64) LOADG(Cr, Cz, Ch, g + 6);
    STEP8(Dr, Dz, Dh, g + 3);
  }
#undef LOADG
#undef STEP8
}

// ---------------- launch ----------------
extern "C" void kernel_launch(void* const* d_in, const int* in_sizes, int n_in,
                              void* d_out, int out_size, void* d_ws, size_t ws_size,
                              hipStream_t stream) {
  const float* x  = (const float*)d_in[0];
  const float* h0 = (const float*)d_in[1];
  const float* kr = (const float*)d_in[2];
  const float* kz = (const float*)d_in[3];
  const float* kh = (const float*)d_in[4];
  const float* mr = (const float*)d_in[5];
  const float* mz = (const float*)d_in[6];
  const float* br = (const float*)d_in[7];
  const float* bz = (const float*)d_in[8];
  float* out = (float*)d_out;

  f16* ws = (f16*)d_ws;

  // per-batch ws need (bytes): x_f16 = 262144, pr/pz/ph = 3*524288 -> 1835008
  size_t avail = ws_size > 786432 ? ws_size - 786432 : 0;
  int Bc = (int)(avail / 1835008ull);
  if (Bc < 1) Bc = 1;
  if (Bc > B_TOT) Bc = B_TOT;

  cvt_w<<<1536, 256, 0, stream>>>(kr, kz, kh, ws);

  for (int b0 = 0; b0 < B_TOT; b0 += Bc) {
    int bc = (Bc < B_TOT - b0) ? Bc : (B_TOT - b0);
    f16* Xf = ws + 393216;
    f16* Pr = Xf + (size_t)bc * 131072;
    f16* Pz = Pr + (size_t)bc * 262144;
    f16* Ph = Pz + (size_t)bc * 262144;

    cvt_x<<<bc * 128, 256, 0, stream>>>(
        (const float4*)(x + (size_t)b0 * 131072), (f16x4*)Xf);
    brc_gemm3<<<bc * 32, 256, 0, stream>>>(Xf, ws, ws + 131072, ws + 262144,
                                           Pr, Pz, Ph, bc * 4);
    brc_scan<<<bc * 2, 256, 0, stream>>>(Pr, Pz, Ph, h0, mr, mz, br, bz, out, b0);
  }
}

// Round 10
// 137.965 us; speedup vs baseline: 1.3843x; 1.2285x over previous
//
#include <hip/hip_runtime.h>

typedef _Float16 f16;
typedef _Float16 f16x8 __attribute__((ext_vector_type(8)));
typedef _Float16 f16x4 __attribute__((ext_vector_type(4)));
typedef float f32x4 __attribute__((ext_vector_type(4)));

#define B_TOT 128

__device__ __forceinline__ float rcpf(float x) { return __builtin_amdgcn_rcpf(x); }

// ---------------- kernel 1: weight convert -> FRAGMENT-ORDERED layout ------
// Wt'[(nt*3+w)*8+kt][kq][ni][rl][8 halfs]:
//   halfs idx = ((((((nt*3+w)*8+kt)*4+kq)*4+ni)*16+rl)*8 + e
// One thread per 16B output chunk (o = 0..49151), coalesced writes.
__global__ void __launch_bounds__(256) cvt_w(const float* __restrict__ Wr,
                                             const float* __restrict__ Wz,
                                             const float* __restrict__ Wh,
                                             f16* __restrict__ out) {
  int o = blockIdx.x * 256 + threadIdx.x;        // < 49152
  int rl = o & 15, ni = (o >> 4) & 3, kq = (o >> 6) & 3, kt = (o >> 8) & 7;
  int wnt = o >> 11;
  int w = wnt % 3, nt = wnt / 3;
  int n = nt * 64 + ni * 16 + rl;
  int k0 = kt * 32 + kq * 8;
  const float* W = (w == 0) ? Wr : ((w == 1) ? Wz : Wh);
  f16x8 v;
#pragma unroll
  for (int e = 0; e < 8; ++e) v[e] = (f16)W[(size_t)(k0 + e) * 512 + n];
  *(f16x8*)(out + (size_t)o * 8) = v;
}

// ---------------- kernel 2: x convert f32->f16, FRAGMENT-ORDERED -----------
// Xf'[m16*8+kt][kq][rl][8 halfs]: halfs idx = (((m16*8+kt)*4+kq)*16+rl)*8 + e
// One thread per 16B out chunk; bc*512*256 halfs / 8 per thread / 256 thr
// = bc*64 blocks.
__global__ void __launch_bounds__(256) cvt_x(const float* __restrict__ in,
                                             f16* __restrict__ out) {
  int o = blockIdx.x * 256 + threadIdx.x;
  int rl = o & 15, kq = (o >> 4) & 3, kt = (o >> 6) & 7, m16 = o >> 9;
  const float* src = in + (size_t)(m16 * 16 + rl) * 256 + kt * 32 + kq * 8;
  f16x8 v;
#pragma unroll
  for (int e = 0; e < 8; ++e) v[e] = (f16)src[e];
  *(f16x8*)(out + (size_t)o * 8) = v;
}

// ---------------- kernel 3: register-streamed 3-weight GEMM ----------------
// ZERO LDS, ZERO barriers. Both operands are L2/L3-resident and fragment-
// ordered, so each MFMA operand is one contiguous 1024B wave-load straight
// to VGPRs. Compiler software-pipelines the fully-unrolled K loop freely.
// BM=128, BN=64 per weight (nt 0..7), 4 waves 2x2 (wave tile 64x32).
// P output CHUNKED: P[bb][tg(64)][h(512)][8t] f16 (scan-friendly).
__global__ void __launch_bounds__(256) brc_gemm3(
    const f16* __restrict__ Af, const f16* __restrict__ Bf,
    f16* __restrict__ Pr, f16* __restrict__ Pz, f16* __restrict__ Ph,
    int Mtiles) {
  const int tid = threadIdx.x;
  const int wid = tid >> 6, lane = tid & 63;
  const int bid = blockIdx.x;
  const int lid = (bid & 7) * Mtiles + (bid >> 3);   // bijective XCD swizzle
  const int mt = lid >> 3, nt = lid & 7;             // m-major: A reuse on-XCD
  const int m0 = mt * 128, n0 = nt * 64;
  const int wr = wid >> 1, wc = wid & 1;

  const int base_m16 = mt * 8 + wr * 4;
  // A: lane-linear within a fragment: byte off = frag*1024 + lane*16
  const char* Ap = (const char*)Af + lane * 16;
  // B: byte off = ((wnt*8+kt)*4+kq)*1024 + nig*256 + rl*16
  const char* Bp = (const char*)Bf + (lane >> 4) * 1024 + (lane & 15) * 16 +
                   (wc * 2) * 256;

  f32x4 acc[3][4][2] = {};

#pragma unroll
  for (int kt = 0; kt < 8; ++kt) {
    f16x8 a[4], b[3][2];
#pragma unroll
    for (int mi = 0; mi < 4; ++mi)
      a[mi] = *(const f16x8*)(Ap + (size_t)((base_m16 + mi) * 8 + kt) * 1024);
#pragma unroll
    for (int w = 0; w < 3; ++w)
#pragma unroll
      for (int ni = 0; ni < 2; ++ni)
        b[w][ni] = *(const f16x8*)(Bp + (size_t)(((nt * 3 + w) * 8 + kt)) * 4096 +
                                   ni * 256);
#pragma unroll
    for (int w = 0; w < 3; ++w)
#pragma unroll
      for (int mi = 0; mi < 4; ++mi)
#pragma unroll
        for (int ni = 0; ni < 2; ++ni)
          acc[w][mi][ni] = __builtin_amdgcn_mfma_f32_16x16x32_f16(
              a[mi], b[w][ni], acc[w][mi][ni], 0, 0, 0);
  }

  // ---- epilogue: C/D layout col = lane&15, row = (lane>>4)*4 + r ----
  const int col = lane & 15;
  const int rbase = (lane >> 4) * 4;
#pragma unroll
  for (int w = 0; w < 3; ++w) {
    f16* P = (w == 0) ? Pr : ((w == 1) ? Pz : Ph);
#pragma unroll
    for (int mi = 0; mi < 4; ++mi) {
      int m = m0 + wr * 64 + mi * 16 + rbase;
      int bbl = m >> 9;
      int t = m & 511;
      size_t base = ((size_t)bbl * 64 + (t >> 3)) * 4096 + (t & 7);
#pragma unroll
      for (int ni = 0; ni < 2; ++ni) {
        int hcol = n0 + wc * 32 + ni * 16 + col;
        f16x4 v;
#pragma unroll
        for (int r = 0; r < 4; ++r) v[r] = (f16)acc[w][mi][ni][r];
        *(f16x4*)&P[base + (size_t)hcol * 8] = v;
      }
    }
  }
}

// ---------------- kernel 4: recurrent scan ----------------
__global__ void __launch_bounds__(256) brc_scan(
    const f16* __restrict__ Pr, const f16* __restrict__ Pz, const f16* __restrict__ Ph,
    const float* __restrict__ h0, const float* __restrict__ mr, const float* __restrict__ mz,
    const float* __restrict__ br, const float* __restrict__ bz,
    float* __restrict__ out, int b0) {
  int gid = blockIdx.x * 256 + threadIdx.x;   // 0 .. bc*512-1
  int bb = gid >> 9;
  int i = gid & 511;
  float h = h0[((size_t)(b0 + bb) << 9) + i];
  float mrc = 2.0f * mr[i], mzc = -mz[i];
  float br2 = 2.0f * br[i], nbz = -bz[i];
  size_t pbase = ((size_t)bb << 18) + (size_t)i * 8;
  const f16* prp = Pr + pbase;
  const f16* pzp = Pz + pbase;
  const f16* php = Ph + pbase;
  float* op = out + (((size_t)(b0 + bb)) << 18) + i;

  f16x8 Ar, Az, Ah, Br_, Bz_, Bh_, Cr, Cz, Ch, Dr, Dz, Dh;

#define LOADG(R, Z, Hh, g)                                              \
  do {                                                                  \
    R  = __builtin_nontemporal_load((const f16x8*)(prp + ((size_t)(g) << 12))); \
    Z  = __builtin_nontemporal_load((const f16x8*)(pzp + ((size_t)(g) << 12))); \
    Hh = __builtin_nontemporal_load((const f16x8*)(php + ((size_t)(g) << 12))); \
  } while (0)

#define STEP8(R, Z, Hh, g)                                              \
  do {                                                                  \
    _Pragma("unroll") for (int j = 0; j < 8; ++j) {                     \
      float prs = fmaf((float)R[j], 2.0f, br2);                         \
      float pzs = fmaf((float)Z[j], -1.0f, nbz);                        \
      float ph2 = (float)Hh[j] * 2.0f;                                  \
      float er = __expf(fmaf(h, mrc, prs));                             \
      float r  = fmaf(-2.0f, rcpf(er + 1.0f), 2.0f);                    \
      float ez = __expf(fmaf(h, mzc, pzs));                             \
      float z  = rcpf(1.0f + ez);                                       \
      float h2 = h + h;                                                 \
      float ec = __expf(fmaf(r, h2, ph2));                              \
      float cd = fmaf(-2.0f, rcpf(ec + 1.0f), 1.0f);                    \
      h = fmaf(z, h - cd, cd);                                          \
      __builtin_nontemporal_store(h, op + ((size_t)((g) * 8 + j) << 9)); \
    }                                                                   \
  } while (0)

  LOADG(Ar, Az, Ah, 0);
  LOADG(Br_, Bz_, Bh_, 1);
  LOADG(Cr, Cz, Ch, 2);
  for (int g = 0; g < 64; g += 4) {
    LOADG(Dr, Dz, Dh, g + 3);
    STEP8(Ar, Az, Ah, g);
    if (g + 4 < 64) LOADG(Ar, Az, Ah, g + 4);
    STEP8(Br_, Bz_, Bh_, g + 1);
    if (g + 5 < 64) LOADG(Br_, Bz_, Bh_, g + 5);
    STEP8(Cr, Cz, Ch, g + 2);
    if (g + 6 < 64) LOADG(Cr, Cz, Ch, g + 6);
    STEP8(Dr, Dz, Dh, g + 3);
  }
#undef LOADG
#undef STEP8
}

// ---------------- launch ----------------
extern "C" void kernel_launch(void* const* d_in, const int* in_sizes, int n_in,
                              void* d_out, int out_size, void* d_ws, size_t ws_size,
                              hipStream_t stream) {
  const float* x  = (const float*)d_in[0];
  const float* h0 = (const float*)d_in[1];
  const float* kr = (const float*)d_in[2];
  const float* kz = (const float*)d_in[3];
  const float* kh = (const float*)d_in[4];
  const float* mr = (const float*)d_in[5];
  const float* mz = (const float*)d_in[6];
  const float* br = (const float*)d_in[7];
  const float* bz = (const float*)d_in[8];
  float* out = (float*)d_out;

  f16* ws = (f16*)d_ws;   // Bf: 393216 halfs = 786 KB

  // per-batch ws need (bytes): x_f16 = 262144, pr/pz/ph = 3*524288 -> 1835008
  size_t avail = ws_size > 786432 ? ws_size - 786432 : 0;
  int Bc = (int)(avail / 1835008ull);
  if (Bc < 1) Bc = 1;
  if (Bc > B_TOT) Bc = B_TOT;

  cvt_w<<<192, 256, 0, stream>>>(kr, kz, kh, ws);

  for (int b0 = 0; b0 < B_TOT; b0 += Bc) {
    int bc = (Bc < B_TOT - b0) ? Bc : (B_TOT - b0);
    f16* Xf = ws + 393216;
    f16* Pr = Xf + (size_t)bc * 131072;
    f16* Pz = Pr + (size_t)bc * 262144;
    f16* Ph = Pz + (size_t)bc * 262144;

    cvt_x<<<bc * 64, 256, 0, stream>>>(x + (size_t)b0 * 131072, Xf);
    brc_gemm3<<<bc * 32, 256, 0, stream>>>(Xf, ws, Pr, Pz, Ph, bc * 4);
    brc_scan<<<bc * 2, 256, 0, stream>>>(Pr, Pz, Ph, h0, mr, mz, br, bz, out, b0);
  }
}